// Round 7
// baseline (164.672 us; speedup 1.0000x reference)
//
#include <hip/hip_runtime.h>
#include <hip/hip_bf16.h>

typedef __bf16    bf16x8 __attribute__((ext_vector_type(8)));
typedef __bf16    bf16x4 __attribute__((ext_vector_type(4)));
typedef _Float16  f16x8  __attribute__((ext_vector_type(8)));
typedef _Float16  f16x4  __attribute__((ext_vector_type(4)));
typedef float     f32x4  __attribute__((ext_vector_type(4)));

#define HL 50
#define DD 64

// ============================ ALGORITHM =================================
// R13 = R12 fused design with ONE change: va_main launch_bounds (256,3) ->
// (256,2).  (256,3)'s 170-VGPR cap was marginal vs the ~160-reg peak live
// set; any spill => private-segment scratch => allocation during hipGraph
// capture => deterministic harness/container failure (rigor.md tripwire).
// (256,2) caps at 256 VGPR: spill impossible, capture-safe.
// Design: no A2/F2/E16 tables (a2e+f2e are L3-resident); main gathers raw
// f32 rows, GEMM1 on the fly:
//   h1 = relu(x_a@W1[0:64] + x_f@W1[128:192] + ba[node]),  ba = b1+rep@W1mid
// GEMM1 C-frags -> GEMM2 A-frags via wave-private LDS repack (no barriers).
// Weighted-sum tail reads raw a2e (L2-hot from GEMM1's gathers).
// Prep: 129 blocks (ba branch + 24 B-fragment combos + scalars).

// ---- prep: [0,GB) bias | last block: 24 B-fragment combos + scalars ----
__global__ __launch_bounds__(256, 4) void prep_all_kernel(
    const int*   __restrict__ nodes,
    const float* __restrict__ v2e,
    const float* __restrict__ W1,
    const float* __restrict__ b1,
    const float* __restrict__ W2,
    const float* __restrict__ b2,
    const float* __restrict__ w3,
    _Float16* __restrict__ ba16,
    _Float16* __restrict__ wf, float* __restrict__ wsc,
    int N, int GB)
{
    __shared__ __align__(16) _Float16 es[64 * 72];    // 9216 B
    const int tid  = threadIdx.x;
    const int w    = tid >> 6, lane = tid & 63;
    const int lq   = lane & 15, quad = lane >> 4;
    const int bid  = blockIdx.x;

    if (bid < GB) {
        // ---- bias branch: ba16[n][c] = f16(b1[c] + rep_n . W1[64:128, c]) ----
        const int col = w * 16 + lq;
        const int n0 = bid * 64;
        #pragma unroll
        for (int i = 0; i < 4; ++i) {
            int t = i * 256 + tid;
            int row = t >> 4, q = t & 15;
            int gn = n0 + row; if (gn >= N) gn = N - 1;
            int idx = nodes[gn];
            float4 v = *(const float4*)(v2e + (size_t)idx * DD + q * 4);
            f16x4 pk = {(_Float16)v.x, (_Float16)v.y, (_Float16)v.z, (_Float16)v.w};
            *(f16x4*)&es[row * 72 + q * 4] = pk;
        }
        f16x8 bfr[2];
        #pragma unroll
        for (int t = 0; t < 2; ++t)
            #pragma unroll
            for (int j = 0; j < 8; ++j)
                bfr[t][j] = (_Float16)W1[(64 + t * 32 + quad * 8 + j) * DD + col];
        const float b1c = b1[col];
        __syncthreads();

        f32x4 acc[4];
        #pragma unroll
        for (int mt = 0; mt < 4; ++mt) acc[mt] = (f32x4){0.f, 0.f, 0.f, 0.f};
        #pragma unroll
        for (int t = 0; t < 2; ++t)
            #pragma unroll
            for (int mt = 0; mt < 4; ++mt) {
                f16x8 a = *(const f16x8*)&es[(mt * 16 + lq) * 72 + t * 32 + quad * 8];
                acc[mt] = __builtin_amdgcn_mfma_f32_16x16x32_f16(a, bfr[t], acc[mt], 0, 0, 0);
            }
        #pragma unroll
        for (int mt = 0; mt < 4; ++mt)
            #pragma unroll
            for (int r = 0; r < 4; ++r) {
                int gn = n0 + mt * 16 + quad * 4 + r;
                if (gn < N) ba16[(size_t)gn * DD + col] = (_Float16)(acc[mt][r] + b1c);
            }
    } else {
        // ---- frag branch: 24 combos.  c<8: W1[0:64) (a-part); c in [8,16):
        // W1[128:192) (f-part); c in [16,24): W2.  Layout = MFMA B-frag:
        // wf[(c*64+lane)*8 + j] = S[(t*32 + quad*8 + j + koff)*64 + ct*16+lq]
        const int ln = tid & 63, c0 = tid >> 6;
        #pragma unroll
        for (int h = 0; h < 6; ++h) {
            int c = c0 + 4 * h;              // 0..23
            int part = c >> 3, cc = c & 7;
            int ct = cc >> 1, t = cc & 1;
            const float* S = (part == 2) ? W2 : W1;
            int koff = (part == 1) ? 128 : 0;
            _Float16* d = wf + ((size_t)c * 64 + ln) * 8;
            #pragma unroll
            for (int j = 0; j < 8; ++j)
                d[j] = (_Float16)S[(koff + t * 32 + (ln >> 4) * 8 + j) * DD
                                   + ct * 16 + (ln & 15)];
        }
        if (tid < 64) { wsc[tid] = w3[tid]; wsc[64 + tid] = b2[tid]; }
    }
}

// ---- main: ONE NODE PER WAVE, fused GEMM1+GEMM2, wave-private LDS ----
__global__ __launch_bounds__(256, 2) void va_main_kernel(
    const int*      __restrict__ hva,
    const int*      __restrict__ haf,
    const float*    __restrict__ a2e,
    const float*    __restrict__ f2e,
    const _Float16* __restrict__ ba16,
    const _Float16* __restrict__ wf,
    const float*    __restrict__ wsc,
    float*          __restrict__ out, int Ntot)
{
    __shared__ __align__(16) _Float16 hs[4][64 * 72];   // 36864 B, wave-private
    const int tid  = threadIdx.x;
    const int w    = tid >> 6;
    const int lane = tid & 63;
    const int lq   = lane & 15;
    const int quad = lane >> 4;
    const int node = blockIdx.x * 4 + w;
    if (node >= Ntot) return;
    _Float16* ws_ = hs[w];

    const int* hb = hva + node * HL;
    const int* fb = haf + node * HL;
    const int lclamp = (lane < HL) ? lane : 0;
    const int iv  = hb[lclamp];                 // lane l holds hva[l]
    const int ifv = fb[lclamp];                 // lane l holds haf[l]

    // ---- burst-gather raw a2e rows for x_a A-fragments (f32, 2xfloat4) ----
    float4 ra[4][2][2];
    #pragma unroll
    for (int mt = 0; mt < 4; ++mt) {
        const int row = mt * 16 + lq;
        const int ia  = __shfl(iv, row);
        #pragma unroll
        for (int t = 0; t < 2; ++t) {
            const float* p = a2e + (size_t)ia * DD + t * 32 + quad * 8;
            ra[mt][t][0] = *(const float4*)p;
            ra[mt][t][1] = *(const float4*)(p + 4);
        }
    }
    // cvt to f16 A-frags (frees the raw burst)
    f16x8 xa[4][2];
    #pragma unroll
    for (int mt = 0; mt < 4; ++mt)
        #pragma unroll
        for (int t = 0; t < 2; ++t) {
            float4 v0 = ra[mt][t][0], v1 = ra[mt][t][1];
            xa[mt][t] = (f16x8){(_Float16)v0.x, (_Float16)v0.y, (_Float16)v0.z, (_Float16)v0.w,
                                (_Float16)v1.x, (_Float16)v1.y, (_Float16)v1.z, (_Float16)v1.w};
        }

    // ---- burst-gather raw f2e rows (in flight under GEMM1-a) ----
    float4 rf[4][2][2];
    #pragma unroll
    for (int mt = 0; mt < 4; ++mt) {
        const int row = mt * 16 + lq;
        const int ifm = __shfl(ifv, row);
        #pragma unroll
        for (int t = 0; t < 2; ++t) {
            const float* p = f2e + (size_t)ifm * DD + t * 32 + quad * 8;
            rf[mt][t][0] = *(const float4*)p;
            rf[mt][t][1] = *(const float4*)(p + 4);
        }
    }

    // ---- GEMM1: acc[mt][ct] = x@W1 + ba, C-layout col=lq, row=quad*4+r ----
    f32x4 acc[4][4];
    #pragma unroll
    for (int ct = 0; ct < 4; ++ct) {
        const float bav = (float)ba16[(size_t)node * DD + ct * 16 + lq];
        #pragma unroll
        for (int mt = 0; mt < 4; ++mt)
            acc[mt][ct] = (f32x4){bav, bav, bav, bav};
    }
    #pragma unroll
    for (int ct = 0; ct < 4; ++ct)
        #pragma unroll
        for (int t = 0; t < 2; ++t) {
            f16x8 bfr = *(const f16x8*)(wf + ((size_t)(ct * 2 + t) * 64 + lane) * 8);
            #pragma unroll
            for (int mt = 0; mt < 4; ++mt)
                acc[mt][ct] = __builtin_amdgcn_mfma_f32_16x16x32_f16(xa[mt][t], bfr, acc[mt][ct], 0, 0, 0);
        }
    // cvt f2e raw -> f16 frags, then f-part MFMAs
    f16x8 xf[4][2];
    #pragma unroll
    for (int mt = 0; mt < 4; ++mt)
        #pragma unroll
        for (int t = 0; t < 2; ++t) {
            float4 v0 = rf[mt][t][0], v1 = rf[mt][t][1];
            xf[mt][t] = (f16x8){(_Float16)v0.x, (_Float16)v0.y, (_Float16)v0.z, (_Float16)v0.w,
                                (_Float16)v1.x, (_Float16)v1.y, (_Float16)v1.z, (_Float16)v1.w};
        }
    #pragma unroll
    for (int ct = 0; ct < 4; ++ct)
        #pragma unroll
        for (int t = 0; t < 2; ++t) {
            f16x8 bfr = *(const f16x8*)(wf + ((size_t)(8 + ct * 2 + t) * 64 + lane) * 8);
            #pragma unroll
            for (int mt = 0; mt < 4; ++mt)
                acc[mt][ct] = __builtin_amdgcn_mfma_f32_16x16x32_f16(xf[mt][t], bfr, acc[mt][ct], 0, 0, 0);
        }

    // ---- relu + repack h1 to wave-private LDS (rows >= HL zeroed) ----
    #pragma unroll
    for (int mt = 0; mt < 4; ++mt)
        #pragma unroll
        for (int ct = 0; ct < 4; ++ct)
            #pragma unroll
            for (int r = 0; r < 4; ++r) {
                const int row = mt * 16 + quad * 4 + r;
                float hv = (row < HL) ? fmaxf(acc[mt][ct][r], 0.f) : 0.f;
                ws_[row * 72 + ct * 16 + lq] = (_Float16)hv;
            }

    // ---- read h1 A-frags back (row = lq), GEMM2 + score partials ----
    f16x8 h1f[4][2];
    #pragma unroll
    for (int mt = 0; mt < 4; ++mt)
        #pragma unroll
        for (int t = 0; t < 2; ++t)
            h1f[mt][t] = *(const f16x8*)&ws_[(mt * 16 + lq) * 72 + t * 32 + quad * 8];

    float sc[4][4];
    #pragma unroll
    for (int mt = 0; mt < 4; ++mt)
        #pragma unroll
        for (int r = 0; r < 4; ++r) sc[mt][r] = 0.f;

    #pragma unroll
    for (int ct = 0; ct < 4; ++ct) {
        const float b2c = wsc[64 + ct * 16 + lq];
        const float w3c = wsc[ct * 16 + lq];
        f16x8 bfr[2];
        #pragma unroll
        for (int t = 0; t < 2; ++t)
            bfr[t] = *(const f16x8*)(wf + ((size_t)(16 + ct * 2 + t) * 64 + lane) * 8);
        #pragma unroll
        for (int mt = 0; mt < 4; ++mt) {
            f32x4 a2 = {b2c, b2c, b2c, b2c};
            #pragma unroll
            for (int t = 0; t < 2; ++t)
                a2 = __builtin_amdgcn_mfma_f32_16x16x32_f16(h1f[mt][t], bfr[t], a2, 0, 0, 0);
            #pragma unroll
            for (int r = 0; r < 4; ++r)
                sc[mt][r] = fmaf(fmaxf(a2[r], 0.f), w3c, sc[mt][r]);
        }
    }

    // ---- reduce scores over lq (each lane then holds its quad's 16 rows) ----
    #pragma unroll
    for (int mt = 0; mt < 4; ++mt)
        #pragma unroll
        for (int r = 0; r < 4; ++r)
            #pragma unroll
            for (int m = 1; m < 16; m <<= 1)
                sc[mt][r] += __shfl_xor(sc[mt][r], m);

    // ---- in-register softmax over 50 rows (row = mt*16 + quad*4 + r) ----
    #pragma unroll
    for (int r = 0; r < 4; ++r)
        if (48 + quad * 4 + r >= HL) sc[3][r] = -3.0e38f;   // rows 50..63

    float mx = sc[0][0];
    #pragma unroll
    for (int mt = 0; mt < 4; ++mt)
        #pragma unroll
        for (int r = 0; r < 4; ++r) mx = fmaxf(mx, sc[mt][r]);
    mx = fmaxf(mx, __shfl_xor(mx, 16));
    mx = fmaxf(mx, __shfl_xor(mx, 32));

    float sm = 0.f;
    #pragma unroll
    for (int mt = 0; mt < 4; ++mt)
        #pragma unroll
        for (int r = 0; r < 4; ++r) {
            sc[mt][r] = __expf(sc[mt][r] - mx);             // 0 for invalid rows
            sm += sc[mt][r];
        }
    sm += __shfl_xor(sm, 16);
    sm += __shfl_xor(sm, 32);
    const float inv = 1.f / sm;

    // ---- weighted e_va sum from raw a2e (rows L2-hot from GEMM1 gather) ----
    float oa[4] = {0.f, 0.f, 0.f, 0.f};
    #pragma unroll
    for (int l = 0; l < HL; ++l) {
        const int   srcl = ((l >> 2) & 3) << 4;             // lane with quad=(l>>2)&3
        const float av   = __shfl(sc[l >> 4][l & 3], srcl);
        const int   idx  = __builtin_amdgcn_readlane(iv, l); // wave-uniform -> SGPR base
        oa[l & 3] = fmaf(av, a2e[(size_t)idx * DD + lane], oa[l & 3]);
    }
    out[(size_t)node * DD + lane] = ((oa[0] + oa[1]) + (oa[2] + oa[3])) * inv;
}

// ======================= FALLBACK (proven R6 path) ======================
#define FMR  112
#define FMT  7
#define FXSS 136

__global__ __launch_bounds__(256) void fb_prep_kernel(
    const float* __restrict__ W1, const float* __restrict__ W2,
    const float* __restrict__ w3, const float* __restrict__ b1,
    const float* __restrict__ b2,
    __bf16* __restrict__ wf, float* __restrict__ wsc)
{
    const int tid  = threadIdx.x;
    const int quad = tid >> 6;
    const int col  = tid & 63;
    __bf16* dst = wf + tid * 64;
    #pragma unroll
    for (int t = 0; t < 4; ++t)
        #pragma unroll
        for (int j = 0; j < 8; ++j) {
            int keff = t * 32 + quad * 8 + j;
            int krow = (keff < 64) ? keff : keff + 64;
            dst[t * 8 + j] = (__bf16)W1[krow * 64 + col];
        }
    #pragma unroll
    for (int t = 0; t < 2; ++t)
        #pragma unroll
        for (int j = 0; j < 8; ++j) {
            dst[32 + t * 8 + j] = (__bf16)W1[(64 + t * 32 + quad * 8 + j) * 64 + col];
            dst[48 + t * 8 + j] = (__bf16)W2[(t * 32 + quad * 8 + j) * 64 + col];
        }
    if (tid < 64) {
        wsc[tid] = w3[tid]; wsc[64 + tid] = b1[tid]; wsc[128 + tid] = b2[tid];
    }
}

__global__ __launch_bounds__(256, 5) void fb_agg_kernel(
    const int* __restrict__ nodes, const int* __restrict__ hva,
    const int* __restrict__ haf, const float* __restrict__ v2e,
    const float* __restrict__ a2e, const float* __restrict__ f2e,
    const __bf16* __restrict__ wf, const float* __restrict__ wsc,
    float* __restrict__ out)
{
    __shared__ __bf16 xs[FMR * FXSS];
    __shared__ float  pbuf[4 * FMR];
    const int tid = threadIdx.x;
    const int w = tid >> 6, lane = tid & 63, lq = lane & 15, quad = lane >> 4;
    const int col = w * 16 + lq;
    const int n0 = blockIdx.x * 2;
    {
        const int* hb = hva + n0 * HL;
        const int* fb = haf + n0 * HL;
        #pragma unroll
        for (int i = 0; i < 13; ++i) {
            int t = i * 256 + tid;
            if (t < 2 * HL * 2 * 16) {
                int r = t >> 4, q = t & 15;
                bool va = (r < 2 * HL);
                int gr = va ? r : r - 2 * HL;
                int idx = va ? hb[gr] : fb[gr];
                const float* src = (va ? a2e : f2e) + (size_t)idx * DD + q * 4;
                float4 v = *(const float4*)src;
                bf16x4 pk = {(__bf16)v.x, (__bf16)v.y, (__bf16)v.z, (__bf16)v.w};
                *(bf16x4*)&xs[gr * FXSS + (va ? 0 : DD) + q * 4] = pk;
            }
        }
    }
    bf16x8 repf[2];
    #pragma unroll
    for (int t = 0; t < 2; ++t)
        #pragma unroll
        for (int j = 0; j < 8; ++j) repf[t][j] = (__bf16)0.f;
    if (lq < 2) {
        int nd = nodes[n0 + lq];
        const float* rp = v2e + (size_t)nd * DD;
        #pragma unroll
        for (int t = 0; t < 2; ++t) {
            float4 v0 = *(const float4*)(rp + t * 32 + quad * 8);
            float4 v1 = *(const float4*)(rp + t * 32 + quad * 8 + 4);
            repf[t] = (bf16x8){(__bf16)v0.x, (__bf16)v0.y, (__bf16)v0.z, (__bf16)v0.w,
                               (__bf16)v1.x, (__bf16)v1.y, (__bf16)v1.z, (__bf16)v1.w};
        }
    }
    const __bf16* fbp = wf + (size_t)(quad * 64 + col) * 64;
    bf16x8 b1f[4], b1u[2], b2f[2];
    #pragma unroll
    for (int t = 0; t < 4; ++t) b1f[t] = *(const bf16x8*)(fbp + t * 8);
    #pragma unroll
    for (int t = 0; t < 2; ++t) {
        b1u[t] = *(const bf16x8*)(fbp + 32 + t * 8);
        b2f[t] = *(const bf16x8*)(fbp + 48 + t * 8);
    }
    const float w3c = wsc[col];
    const float b1c = wsc[64 + col];
    const float b2c = wsc[128 + col];
    f32x4 rb = {0.f, 0.f, 0.f, 0.f};
    #pragma unroll
    for (int t = 0; t < 2; ++t)
        rb = __builtin_amdgcn_mfma_f32_16x16x32_bf16(repf[t], b1u[t], rb, 0, 0, 0);
    const float bias0 = __shfl(rb[0], lq) + b1c;
    const float bias1 = __shfl(rb[1], lq) + b1c;
    __syncthreads();
    f32x4 acc[FMT];
    #pragma unroll
    for (int mt = 0; mt < FMT; ++mt)
        #pragma unroll
        for (int r = 0; r < 4; ++r) {
            int gr = mt * 16 + quad * 4 + r;
            acc[mt][r] = (gr >= HL) ? bias1 : bias0;
        }
    #pragma unroll
    for (int t = 0; t < 4; ++t)
        #pragma unroll
        for (int mt = 0; mt < FMT; ++mt) {
            bf16x8 a = *(const bf16x8*)&xs[(mt * 16 + lq) * FXSS + t * 32 + quad * 8];
            acc[mt] = __builtin_amdgcn_mfma_f32_16x16x32_bf16(a, b1f[t], acc[mt], 0, 0, 0);
        }
    __syncthreads();
    #pragma unroll
    for (int mt = 0; mt < FMT; ++mt)
        #pragma unroll
        for (int r = 0; r < 4; ++r) {
            int gr = mt * 16 + quad * 4 + r;
            xs[gr * FXSS + DD + col] = (__bf16)fmaxf(acc[mt][r], 0.f);
        }
    __syncthreads();
    f32x4 a2[FMT];
    #pragma unroll
    for (int mt = 0; mt < FMT; ++mt) a2[mt] = (f32x4){b2c, b2c, b2c, b2c};
    #pragma unroll
    for (int t = 0; t < 2; ++t)
        #pragma unroll
        for (int mt = 0; mt < FMT; ++mt) {
            bf16x8 a = *(const bf16x8*)&xs[(mt * 16 + lq) * FXSS + DD + t * 32 + quad * 8];
            a2[mt] = __builtin_amdgcn_mfma_f32_16x16x32_bf16(a, b2f[t], a2[mt], 0, 0, 0);
        }
    #pragma unroll
    for (int mt = 0; mt < FMT; ++mt) {
        float p0 = fmaxf(a2[mt][0], 0.f) * w3c;
        float p1 = fmaxf(a2[mt][1], 0.f) * w3c;
        float p2 = fmaxf(a2[mt][2], 0.f) * w3c;
        float p3 = fmaxf(a2[mt][3], 0.f) * w3c;
        #pragma unroll
        for (int m = 1; m < 16; m <<= 1) {
            p0 += __shfl_xor(p0, m); p1 += __shfl_xor(p1, m);
            p2 += __shfl_xor(p2, m); p3 += __shfl_xor(p3, m);
        }
        if (lq == 0) {
            int rowb = mt * 16 + quad * 4;
            pbuf[w * FMR + rowb + 0] = p0; pbuf[w * FMR + rowb + 1] = p1;
            pbuf[w * FMR + rowb + 2] = p2; pbuf[w * FMR + rowb + 3] = p3;
        }
    }
    __syncthreads();
    const int n = w & 1, lh = w >> 1;
    float att;
    {
        float s = -3.0e38f;
        if (lane < HL) {
            int gr = n * HL + lane;
            s = pbuf[gr] + pbuf[FMR + gr] + pbuf[2 * FMR + gr] + pbuf[3 * FMR + gr];
        }
        float mx = s;
        #pragma unroll
        for (int m = 1; m < 64; m <<= 1) mx = fmaxf(mx, __shfl_xor(mx, m));
        float e = (lane < HL) ? __expf(s - mx) : 0.f;
        float sm = e;
        #pragma unroll
        for (int m = 1; m < 64; m <<= 1) sm += __shfl_xor(sm, m);
        att = e / sm;
    }
    {
        float o = 0.f;
        const int lb = lh * 25;
        #pragma unroll
        for (int i = 0; i < 25; ++i) {
            int l = lb + i;
            float av = __shfl(att, l);
            o = fmaf(av, (float)xs[(n * HL + l) * FXSS + lane], o);
        }
        float* op = (float*)&xs[(100 + w) * FXSS + DD];
        op[lane] = o;
    }
    __syncthreads();
    if (w < 2) {
        const float* p0 = (const float*)&xs[(100 + w) * FXSS + DD];
        const float* p1 = (const float*)&xs[(100 + w + 2) * FXSS + DD];
        out[(size_t)(n0 + w) * DD + lane] = p0[lane] + p1[lane];
    }
}

// ================================ host ==================================
extern "C" void kernel_launch(void* const* d_in, const int* in_sizes, int n_in,
                              void* d_out, int out_size, void* d_ws, size_t ws_size,
                              hipStream_t stream) {
    const int*   nodes = (const int*)d_in[0];
    const int*   hva   = (const int*)d_in[1];
    const int*   haf   = (const int*)d_in[2];
    const float* v2e   = (const float*)d_in[3];
    const float* a2e   = (const float*)d_in[4];
    const float* f2e   = (const float*)d_in[5];
    const float* W1    = (const float*)d_in[6];
    const float* b1    = (const float*)d_in[7];
    const float* W2    = (const float*)d_in[8];
    const float* b2    = (const float*)d_in[9];
    const float* w3    = (const float*)d_in[10];
    // d_in[11] = b3: softmax shift-invariant — unused.
    float* out = (float*)d_out;

    const int N  = in_sizes[0];            // 8192

    size_t offBA = 0;                                     // N x 64 f16
    size_t offWF = (offBA + (size_t)N * DD * 2 + 255) & ~(size_t)255;
    size_t offSC = offWF + 24 * 64 * 8 * 2;               // 24 frag combos
    size_t need  = offSC + 128 * 4;

    if (ws_size >= need) {
        _Float16* ba  = (_Float16*)((char*)d_ws + offBA);
        _Float16* wfr = (_Float16*)((char*)d_ws + offWF);
        float*    wsc = (float*)((char*)d_ws + offSC);

        const int GB = (N + 63) / 64;
        prep_all_kernel<<<GB + 1, 256, 0, stream>>>(
            nodes, v2e, W1, b1, W2, b2, w3, ba, wfr, wsc, N, GB);
        va_main_kernel<<<(N + 3) / 4, 256, 0, stream>>>(
            hva, haf, a2e, f2e, ba, wfr, wsc, out, N);
    } else {
        // workspace too small — proven R6 fallback (33 KB)
        __bf16* wf  = (__bf16*)d_ws;
        float*  wsc = (float*)((char*)d_ws + 256 * 64 * 2);
        fb_prep_kernel<<<1, 256, 0, stream>>>(W1, W2, w3, b1, b2, wf, wsc);
        fb_agg_kernel<<<N / 2, 256, 0, stream>>>(nodes, hva, haf, v2e, a2e, f2e,
                                                 wf, wsc, out);
    }
}

// Round 8
// 159.152 us; speedup vs baseline: 1.0347x; 1.0347x over previous
//
#include <hip/hip_runtime.h>
#include <hip/hip_bf16.h>

typedef __bf16    bf16x8 __attribute__((ext_vector_type(8)));
typedef __bf16    bf16x4 __attribute__((ext_vector_type(4)));
typedef _Float16  f16x8  __attribute__((ext_vector_type(8)));
typedef _Float16  f16x4  __attribute__((ext_vector_type(4)));
typedef float     f32x4  __attribute__((ext_vector_type(4)));

#define HL 50
#define DD 64

// ============================ ALGORITHM =================================
// R14: fused GEMM1+GEMM2 main (R13 structure) but gathering F16 TABLES.
// R13's raw-f32 gathers doubled fetch (141 MB) -> 64us main.  Now prep is
// a pure streaming cvt: A16=f16(a2e), F16=f16(f2e) (77 MB at stream BW,
// no MFMA/LDS/barriers), and main gathers f16 rows (half the bytes,
// same rounding as R13's in-kernel cvt).  A16 doubles as the e_va table
// for the weighted-sum tail (rows L2-hot from GEMM1's gathers).
// h1 = relu(A16[va]@W1a + F16[af]@W1f + ba[node]), ba = b1 + rep@W1mid.
// va_main keeps launch_bounds(256,2) — (256,3) caused spill-during-
// graph-capture container failures (R12/R13 bisection).

// ---- prep: [0,GC) cvt stream | [GC,GC+GB) bias | last: frag combos ----
__global__ __launch_bounds__(256, 4) void prep_all_kernel(
    const int*   __restrict__ nodes,
    const float* __restrict__ v2e,
    const float* __restrict__ a2e,
    const float* __restrict__ f2e,
    const float* __restrict__ W1,
    const float* __restrict__ b1,
    const float* __restrict__ W2,
    const float* __restrict__ b2,
    const float* __restrict__ w3,
    _Float16* __restrict__ A16, _Float16* __restrict__ F16,
    _Float16* __restrict__ ba16,
    _Float16* __restrict__ wf, float* __restrict__ wsc,
    int nA, int nF, int N, int GC, int GB)
{
    __shared__ __align__(16) _Float16 es[64 * 72];    // 9216 B (bias branch)
    const int tid  = threadIdx.x;
    const int w    = tid >> 6, lane = tid & 63;
    const int lq   = lane & 15, quad = lane >> 4;
    const int bid  = blockIdx.x;

    if (bid < GC) {
        // ---- pure streaming cvt: f32 -> f16, float4-chunk grid-stride ----
        const size_t total = (size_t)(nA + nF) * 16;   // 16 float4-chunks/row
        for (size_t c = (size_t)bid * 256 + tid; c < total;
             c += (size_t)GC * 256) {
            const size_t row = c >> 4;
            const int    seg = (int)(c & 15);
            const float* s;
            _Float16*    d;
            if (row < (size_t)nA) {
                s = a2e + row * DD + seg * 4;
                d = A16 + row * DD + seg * 4;
            } else {
                const size_t r2 = row - (size_t)nA;
                s = f2e + r2 * DD + seg * 4;
                d = F16 + r2 * DD + seg * 4;
            }
            float4 v = *(const float4*)s;
            f16x4 pk = {(_Float16)v.x, (_Float16)v.y, (_Float16)v.z, (_Float16)v.w};
            *(f16x4*)d = pk;
        }
    } else if (bid < GC + GB) {
        // ---- bias branch: ba16[n][c] = f16(b1[c] + rep_n . W1[64:128, c]) ----
        const int col = w * 16 + lq;
        const int n0 = (bid - GC) * 64;
        #pragma unroll
        for (int i = 0; i < 4; ++i) {
            int t = i * 256 + tid;
            int row = t >> 4, q = t & 15;
            int gn = n0 + row; if (gn >= N) gn = N - 1;
            int idx = nodes[gn];
            float4 v = *(const float4*)(v2e + (size_t)idx * DD + q * 4);
            f16x4 pk = {(_Float16)v.x, (_Float16)v.y, (_Float16)v.z, (_Float16)v.w};
            *(f16x4*)&es[row * 72 + q * 4] = pk;
        }
        f16x8 bfr[2];
        #pragma unroll
        for (int t = 0; t < 2; ++t)
            #pragma unroll
            for (int j = 0; j < 8; ++j)
                bfr[t][j] = (_Float16)W1[(64 + t * 32 + quad * 8 + j) * DD + col];
        const float b1c = b1[col];
        __syncthreads();

        f32x4 acc[4];
        #pragma unroll
        for (int mt = 0; mt < 4; ++mt) acc[mt] = (f32x4){0.f, 0.f, 0.f, 0.f};
        #pragma unroll
        for (int t = 0; t < 2; ++t)
            #pragma unroll
            for (int mt = 0; mt < 4; ++mt) {
                f16x8 a = *(const f16x8*)&es[(mt * 16 + lq) * 72 + t * 32 + quad * 8];
                acc[mt] = __builtin_amdgcn_mfma_f32_16x16x32_f16(a, bfr[t], acc[mt], 0, 0, 0);
            }
        #pragma unroll
        for (int mt = 0; mt < 4; ++mt)
            #pragma unroll
            for (int r = 0; r < 4; ++r) {
                int gn = n0 + mt * 16 + quad * 4 + r;
                if (gn < N) ba16[(size_t)gn * DD + col] = (_Float16)(acc[mt][r] + b1c);
            }
    } else {
        // ---- frag branch: 24 combos.  c<8: W1[0:64) (a-part); c in [8,16):
        // W1[128:192) (f-part); c in [16,24): W2.  Layout = MFMA B-frag.
        const int ln = tid & 63, c0 = tid >> 6;
        #pragma unroll
        for (int h = 0; h < 6; ++h) {
            int c = c0 + 4 * h;              // 0..23
            int part = c >> 3, cc = c & 7;
            int ct = cc >> 1, t = cc & 1;
            const float* S = (part == 2) ? W2 : W1;
            int koff = (part == 1) ? 128 : 0;
            _Float16* d = wf + ((size_t)c * 64 + ln) * 8;
            #pragma unroll
            for (int j = 0; j < 8; ++j)
                d[j] = (_Float16)S[(koff + t * 32 + (ln >> 4) * 8 + j) * DD
                                   + ct * 16 + (ln & 15)];
        }
        if (tid < 64) { wsc[tid] = w3[tid]; wsc[64 + tid] = b2[tid]; }
    }
}

// ---- main: ONE NODE PER WAVE, fused GEMM1+GEMM2, f16 table gathers ----
__global__ __launch_bounds__(256, 2) void va_main_kernel(
    const int*      __restrict__ hva,
    const int*      __restrict__ haf,
    const _Float16* __restrict__ A16,
    const _Float16* __restrict__ F16,
    const _Float16* __restrict__ ba16,
    const _Float16* __restrict__ wf,
    const float*    __restrict__ wsc,
    float*          __restrict__ out, int Ntot)
{
    __shared__ __align__(16) _Float16 hs[4][64 * 72];   // 36864 B, wave-private
    const int tid  = threadIdx.x;
    const int w    = tid >> 6;
    const int lane = tid & 63;
    const int lq   = lane & 15;
    const int quad = lane >> 4;
    const int node = blockIdx.x * 4 + w;
    if (node >= Ntot) return;
    _Float16* ws_ = hs[w];

    const int* hb = hva + node * HL;
    const int* fb = haf + node * HL;
    const int lclamp = (lane < HL) ? lane : 0;
    const int iv  = hb[lclamp];                 // lane l holds hva[l]
    const int ifv = fb[lclamp];                 // lane l holds haf[l]

    // ---- burst-gather f16 A16/F16 rows for A-fragments (2x f16x8/row) ----
    f16x8 xa[4][2], xf[4][2];
    #pragma unroll
    for (int mt = 0; mt < 4; ++mt) {
        const int row = mt * 16 + lq;
        const int ia  = __shfl(iv,  row);
        const int ifm = __shfl(ifv, row);
        #pragma unroll
        for (int t = 0; t < 2; ++t) {
            xa[mt][t] = *(const f16x8*)(A16 + (size_t)ia  * DD + t * 32 + quad * 8);
            xf[mt][t] = *(const f16x8*)(F16 + (size_t)ifm * DD + t * 32 + quad * 8);
        }
    }

    // ---- GEMM1: acc[mt][ct] = x@W1 + ba, C-layout col=lq, row=quad*4+r ----
    f32x4 acc[4][4];
    #pragma unroll
    for (int ct = 0; ct < 4; ++ct) {
        const float bav = (float)ba16[(size_t)node * DD + ct * 16 + lq];
        #pragma unroll
        for (int mt = 0; mt < 4; ++mt)
            acc[mt][ct] = (f32x4){bav, bav, bav, bav};
    }
    #pragma unroll
    for (int ct = 0; ct < 4; ++ct)
        #pragma unroll
        for (int t = 0; t < 2; ++t) {
            f16x8 bfr = *(const f16x8*)(wf + ((size_t)(ct * 2 + t) * 64 + lane) * 8);
            #pragma unroll
            for (int mt = 0; mt < 4; ++mt)
                acc[mt][ct] = __builtin_amdgcn_mfma_f32_16x16x32_f16(xa[mt][t], bfr, acc[mt][ct], 0, 0, 0);
        }
    #pragma unroll
    for (int ct = 0; ct < 4; ++ct)
        #pragma unroll
        for (int t = 0; t < 2; ++t) {
            f16x8 bfr = *(const f16x8*)(wf + ((size_t)(8 + ct * 2 + t) * 64 + lane) * 8);
            #pragma unroll
            for (int mt = 0; mt < 4; ++mt)
                acc[mt][ct] = __builtin_amdgcn_mfma_f32_16x16x32_f16(xf[mt][t], bfr, acc[mt][ct], 0, 0, 0);
        }

    // ---- relu + repack h1 to wave-private LDS (rows >= HL zeroed) ----
    #pragma unroll
    for (int mt = 0; mt < 4; ++mt)
        #pragma unroll
        for (int ct = 0; ct < 4; ++ct)
            #pragma unroll
            for (int r = 0; r < 4; ++r) {
                const int row = mt * 16 + quad * 4 + r;
                float hv = (row < HL) ? fmaxf(acc[mt][ct][r], 0.f) : 0.f;
                ws_[row * 72 + ct * 16 + lq] = (_Float16)hv;
            }

    // ---- read h1 A-frags back (row = lq), GEMM2 + score partials ----
    f16x8 h1f[4][2];
    #pragma unroll
    for (int mt = 0; mt < 4; ++mt)
        #pragma unroll
        for (int t = 0; t < 2; ++t)
            h1f[mt][t] = *(const f16x8*)&ws_[(mt * 16 + lq) * 72 + t * 32 + quad * 8];

    float sc[4][4];
    #pragma unroll
    for (int mt = 0; mt < 4; ++mt)
        #pragma unroll
        for (int r = 0; r < 4; ++r) sc[mt][r] = 0.f;

    #pragma unroll
    for (int ct = 0; ct < 4; ++ct) {
        const float b2c = wsc[64 + ct * 16 + lq];
        const float w3c = wsc[ct * 16 + lq];
        f16x8 bfr[2];
        #pragma unroll
        for (int t = 0; t < 2; ++t)
            bfr[t] = *(const f16x8*)(wf + ((size_t)(16 + ct * 2 + t) * 64 + lane) * 8);
        #pragma unroll
        for (int mt = 0; mt < 4; ++mt) {
            f32x4 a2 = {b2c, b2c, b2c, b2c};
            #pragma unroll
            for (int t = 0; t < 2; ++t)
                a2 = __builtin_amdgcn_mfma_f32_16x16x32_f16(h1f[mt][t], bfr[t], a2, 0, 0, 0);
            #pragma unroll
            for (int r = 0; r < 4; ++r)
                sc[mt][r] = fmaf(fmaxf(a2[r], 0.f), w3c, sc[mt][r]);
        }
    }

    // ---- reduce scores over lq (each lane then holds its quad's 16 rows) ----
    #pragma unroll
    for (int mt = 0; mt < 4; ++mt)
        #pragma unroll
        for (int r = 0; r < 4; ++r)
            #pragma unroll
            for (int m = 1; m < 16; m <<= 1)
                sc[mt][r] += __shfl_xor(sc[mt][r], m);

    // ---- in-register softmax over 50 rows (row = mt*16 + quad*4 + r) ----
    #pragma unroll
    for (int r = 0; r < 4; ++r)
        if (48 + quad * 4 + r >= HL) sc[3][r] = -3.0e38f;   // rows 50..63

    float mx = sc[0][0];
    #pragma unroll
    for (int mt = 0; mt < 4; ++mt)
        #pragma unroll
        for (int r = 0; r < 4; ++r) mx = fmaxf(mx, sc[mt][r]);
    mx = fmaxf(mx, __shfl_xor(mx, 16));
    mx = fmaxf(mx, __shfl_xor(mx, 32));

    float sm = 0.f;
    #pragma unroll
    for (int mt = 0; mt < 4; ++mt)
        #pragma unroll
        for (int r = 0; r < 4; ++r) {
            sc[mt][r] = __expf(sc[mt][r] - mx);             // 0 for invalid rows
            sm += sc[mt][r];
        }
    sm += __shfl_xor(sm, 16);
    sm += __shfl_xor(sm, 32);
    const float inv = 1.f / sm;

    // ---- weighted e_va sum from A16 (rows L2-hot from GEMM1 gather) ----
    float oa[4] = {0.f, 0.f, 0.f, 0.f};
    #pragma unroll
    for (int l = 0; l < HL; ++l) {
        const int   srcl = ((l >> 2) & 3) << 4;             // lane with quad=(l>>2)&3
        const float av   = __shfl(sc[l >> 4][l & 3], srcl);
        const int   idx  = __builtin_amdgcn_readlane(iv, l); // wave-uniform -> SGPR base
        oa[l & 3] = fmaf(av, (float)A16[(size_t)idx * DD + lane], oa[l & 3]);
    }
    out[(size_t)node * DD + lane] = ((oa[0] + oa[1]) + (oa[2] + oa[3])) * inv;
}

// ======================= FALLBACK (proven R6 path) ======================
#define FMR  112
#define FMT  7
#define FXSS 136

__global__ __launch_bounds__(256) void fb_prep_kernel(
    const float* __restrict__ W1, const float* __restrict__ W2,
    const float* __restrict__ w3, const float* __restrict__ b1,
    const float* __restrict__ b2,
    __bf16* __restrict__ wf, float* __restrict__ wsc)
{
    const int tid  = threadIdx.x;
    const int quad = tid >> 6;
    const int col  = tid & 63;
    __bf16* dst = wf + tid * 64;
    #pragma unroll
    for (int t = 0; t < 4; ++t)
        #pragma unroll
        for (int j = 0; j < 8; ++j) {
            int keff = t * 32 + quad * 8 + j;
            int krow = (keff < 64) ? keff : keff + 64;
            dst[t * 8 + j] = (__bf16)W1[krow * 64 + col];
        }
    #pragma unroll
    for (int t = 0; t < 2; ++t)
        #pragma unroll
        for (int j = 0; j < 8; ++j) {
            dst[32 + t * 8 + j] = (__bf16)W1[(64 + t * 32 + quad * 8 + j) * 64 + col];
            dst[48 + t * 8 + j] = (__bf16)W2[(t * 32 + quad * 8 + j) * 64 + col];
        }
    if (tid < 64) {
        wsc[tid] = w3[tid]; wsc[64 + tid] = b1[tid]; wsc[128 + tid] = b2[tid];
    }
}

__global__ __launch_bounds__(256, 5) void fb_agg_kernel(
    const int* __restrict__ nodes, const int* __restrict__ hva,
    const int* __restrict__ haf, const float* __restrict__ v2e,
    const float* __restrict__ a2e, const float* __restrict__ f2e,
    const __bf16* __restrict__ wf, const float* __restrict__ wsc,
    float* __restrict__ out)
{
    __shared__ __bf16 xs[FMR * FXSS];
    __shared__ float  pbuf[4 * FMR];
    const int tid = threadIdx.x;
    const int w = tid >> 6, lane = tid & 63, lq = lane & 15, quad = lane >> 4;
    const int col = w * 16 + lq;
    const int n0 = blockIdx.x * 2;
    {
        const int* hb = hva + n0 * HL;
        const int* fb = haf + n0 * HL;
        #pragma unroll
        for (int i = 0; i < 13; ++i) {
            int t = i * 256 + tid;
            if (t < 2 * HL * 2 * 16) {
                int r = t >> 4, q = t & 15;
                bool va = (r < 2 * HL);
                int gr = va ? r : r - 2 * HL;
                int idx = va ? hb[gr] : fb[gr];
                const float* src = (va ? a2e : f2e) + (size_t)idx * DD + q * 4;
                float4 v = *(const float4*)src;
                bf16x4 pk = {(__bf16)v.x, (__bf16)v.y, (__bf16)v.z, (__bf16)v.w};
                *(bf16x4*)&xs[gr * FXSS + (va ? 0 : DD) + q * 4] = pk;
            }
        }
    }
    bf16x8 repf[2];
    #pragma unroll
    for (int t = 0; t < 2; ++t)
        #pragma unroll
        for (int j = 0; j < 8; ++j) repf[t][j] = (__bf16)0.f;
    if (lq < 2) {
        int nd = nodes[n0 + lq];
        const float* rp = v2e + (size_t)nd * DD;
        #pragma unroll
        for (int t = 0; t < 2; ++t) {
            float4 v0 = *(const float4*)(rp + t * 32 + quad * 8);
            float4 v1 = *(const float4*)(rp + t * 32 + quad * 8 + 4);
            repf[t] = (bf16x8){(__bf16)v0.x, (__bf16)v0.y, (__bf16)v0.z, (__bf16)v0.w,
                               (__bf16)v1.x, (__bf16)v1.y, (__bf16)v1.z, (__bf16)v1.w};
        }
    }
    const __bf16* fbp = wf + (size_t)(quad * 64 + col) * 64;
    bf16x8 b1f[4], b1u[2], b2f[2];
    #pragma unroll
    for (int t = 0; t < 4; ++t) b1f[t] = *(const bf16x8*)(fbp + t * 8);
    #pragma unroll
    for (int t = 0; t < 2; ++t) {
        b1u[t] = *(const bf16x8*)(fbp + 32 + t * 8);
        b2f[t] = *(const bf16x8*)(fbp + 48 + t * 8);
    }
    const float w3c = wsc[col];
    const float b1c = wsc[64 + col];
    const float b2c = wsc[128 + col];
    f32x4 rb = {0.f, 0.f, 0.f, 0.f};
    #pragma unroll
    for (int t = 0; t < 2; ++t)
        rb = __builtin_amdgcn_mfma_f32_16x16x32_bf16(repf[t], b1u[t], rb, 0, 0, 0);
    const float bias0 = __shfl(rb[0], lq) + b1c;
    const float bias1 = __shfl(rb[1], lq) + b1c;
    __syncthreads();
    f32x4 acc[FMT];
    #pragma unroll
    for (int mt = 0; mt < FMT; ++mt)
        #pragma unroll
        for (int r = 0; r < 4; ++r) {
            int gr = mt * 16 + quad * 4 + r;
            acc[mt][r] = (gr >= HL) ? bias1 : bias0;
        }
    #pragma unroll
    for (int t = 0; t < 4; ++t)
        #pragma unroll
        for (int mt = 0; mt < FMT; ++mt) {
            bf16x8 a = *(const bf16x8*)&xs[(mt * 16 + lq) * FXSS + t * 32 + quad * 8];
            acc[mt] = __builtin_amdgcn_mfma_f32_16x16x32_bf16(a, b1f[t], acc[mt], 0, 0, 0);
        }
    __syncthreads();
    #pragma unroll
    for (int mt = 0; mt < FMT; ++mt)
        #pragma unroll
        for (int r = 0; r < 4; ++r) {
            int gr = mt * 16 + quad * 4 + r;
            xs[gr * FXSS + DD + col] = (__bf16)fmaxf(acc[mt][r], 0.f);
        }
    __syncthreads();
    f32x4 a2[FMT];
    #pragma unroll
    for (int mt = 0; mt < FMT; ++mt) a2[mt] = (f32x4){b2c, b2c, b2c, b2c};
    #pragma unroll
    for (int t = 0; t < 2; ++t)
        #pragma unroll
        for (int mt = 0; mt < FMT; ++mt) {
            bf16x8 a = *(const bf16x8*)&xs[(mt * 16 + lq) * FXSS + DD + t * 32 + quad * 8];
            a2[mt] = __builtin_amdgcn_mfma_f32_16x16x32_bf16(a, b2f[t], a2[mt], 0, 0, 0);
        }
    #pragma unroll
    for (int mt = 0; mt < FMT; ++mt) {
        float p0 = fmaxf(a2[mt][0], 0.f) * w3c;
        float p1 = fmaxf(a2[mt][1], 0.f) * w3c;
        float p2 = fmaxf(a2[mt][2], 0.f) * w3c;
        float p3 = fmaxf(a2[mt][3], 0.f) * w3c;
        #pragma unroll
        for (int m = 1; m < 16; m <<= 1) {
            p0 += __shfl_xor(p0, m); p1 += __shfl_xor(p1, m);
            p2 += __shfl_xor(p2, m); p3 += __shfl_xor(p3, m);
        }
        if (lq == 0) {
            int rowb = mt * 16 + quad * 4;
            pbuf[w * FMR + rowb + 0] = p0; pbuf[w * FMR + rowb + 1] = p1;
            pbuf[w * FMR + rowb + 2] = p2; pbuf[w * FMR + rowb + 3] = p3;
        }
    }
    __syncthreads();
    const int n = w & 1, lh = w >> 1;
    float att;
    {
        float s = -3.0e38f;
        if (lane < HL) {
            int gr = n * HL + lane;
            s = pbuf[gr] + pbuf[FMR + gr] + pbuf[2 * FMR + gr] + pbuf[3 * FMR + gr];
        }
        float mx = s;
        #pragma unroll
        for (int m = 1; m < 64; m <<= 1) mx = fmaxf(mx, __shfl_xor(mx, m));
        float e = (lane < HL) ? __expf(s - mx) : 0.f;
        float sm = e;
        #pragma unroll
        for (int m = 1; m < 64; m <<= 1) sm += __shfl_xor(sm, m);
        att = e / sm;
    }
    {
        float o = 0.f;
        const int lb = lh * 25;
        #pragma unroll
        for (int i = 0; i < 25; ++i) {
            int l = lb + i;
            float av = __shfl(att, l);
            o = fmaf(av, (float)xs[(n * HL + l) * FXSS + lane], o);
        }
        float* op = (float*)&xs[(100 + w) * FXSS + DD];
        op[lane] = o;
    }
    __syncthreads();
    if (w < 2) {
        const float* p0 = (const float*)&xs[(100 + w) * FXSS + DD];
        const float* p1 = (const float*)&xs[(100 + w + 2) * FXSS + DD];
        out[(size_t)(n0 + w) * DD + lane] = p0[lane] + p1[lane];
    }
}

// ================================ host ==================================
extern "C" void kernel_launch(void* const* d_in, const int* in_sizes, int n_in,
                              void* d_out, int out_size, void* d_ws, size_t ws_size,
                              hipStream_t stream) {
    const int*   nodes = (const int*)d_in[0];
    const int*   hva   = (const int*)d_in[1];
    const int*   haf   = (const int*)d_in[2];
    const float* v2e   = (const float*)d_in[3];
    const float* a2e   = (const float*)d_in[4];
    const float* f2e   = (const float*)d_in[5];
    const float* W1    = (const float*)d_in[6];
    const float* b1    = (const float*)d_in[7];
    const float* W2    = (const float*)d_in[8];
    const float* b2    = (const float*)d_in[9];
    const float* w3    = (const float*)d_in[10];
    // d_in[11] = b3: softmax shift-invariant — unused.
    float* out = (float*)d_out;

    const int N  = in_sizes[0];            // 8192
    const int nA = in_sizes[4] / DD;       // 100000
    const int nF = in_sizes[5] / DD;       // 100000

    size_t offA  = 0;                                     // nA x 64 f16
    size_t offF  = (offA + (size_t)nA * DD * 2 + 255) & ~(size_t)255;
    size_t offBA = (offF + (size_t)nF * DD * 2 + 255) & ~(size_t)255;
    size_t offWF = (offBA + (size_t)N * DD * 2 + 255) & ~(size_t)255;
    size_t offSC = offWF + 24 * 64 * 8 * 2;               // 24 frag combos
    size_t need  = offSC + 128 * 4;

    if (ws_size >= need) {
        _Float16* A16 = (_Float16*)((char*)d_ws + offA);
        _Float16* F16 = (_Float16*)((char*)d_ws + offF);
        _Float16* ba  = (_Float16*)((char*)d_ws + offBA);
        _Float16* wfr = (_Float16*)((char*)d_ws + offWF);
        float*    wsc = (float*)((char*)d_ws + offSC);

        const int GC = 2048;               // cvt-stream blocks
        const int GB = (N + 63) / 64;
        prep_all_kernel<<<GC + GB + 1, 256, 0, stream>>>(
            nodes, v2e, a2e, f2e, W1, b1, W2, b2, w3,
            A16, F16, ba, wfr, wsc, nA, nF, N, GC, GB);
        va_main_kernel<<<(N + 3) / 4, 256, 0, stream>>>(
            hva, haf, A16, F16, ba, wfr, wsc, out, N);
    } else {
        // workspace too small — proven R6 fallback (33 KB)
        __bf16* wf  = (__bf16*)d_ws;
        float*  wsc = (float*)((char*)d_ws + 256 * 64 * 2);
        fb_prep_kernel<<<1, 256, 0, stream>>>(W1, W2, w3, b1, b2, wf, wsc);
        fb_agg_kernel<<<N / 2, 256, 0, stream>>>(nodes, hva, haf, v2e, a2e, f2e,
                                                 wf, wsc, out);
    }
}